// Round 6
// baseline (347.145 us; speedup 1.0000x reference)
//
#include <hip/hip_runtime.h>
#include <hip/hip_bf16.h>

// Problem: B=8192, D_IN=1024, D_OUT=1024, E=16
#define NB 8192
#define DIN 1024
#define DOUT 1024
#define NE 16

// GEMM tile geometry: split-K=2 (8 experts per block), BM=BN=256, BK=64
#define BM 256
#define BN 256
#define BK 64
#define NT 128  // (8 experts * 1024) / 64

typedef __attribute__((ext_vector_type(8))) short bf16x8;
typedef __attribute__((ext_vector_type(4))) short short4_t;
typedef __attribute__((ext_vector_type(4))) float f32x4;

__device__ __forceinline__ unsigned short f32_to_bf16(float f) {
  unsigned int u = __float_as_uint(f);
  u += 0x7FFFu + ((u >> 16) & 1u);  // RNE
  return (unsigned short)(u >> 16);
}

__device__ __forceinline__ void gl_lds16(const void* gp, void* lp) {
  __builtin_amdgcn_global_load_lds(
      (const __attribute__((address_space(1))) void*)gp,
      (__attribute__((address_space(3))) void*)lp, 16, 0, 0);
}

// direct global->VGPR 16B load; completion ordered by our explicit vmcnt
__device__ __forceinline__ void gload16(bf16x8& d, const unsigned short* p) {
  asm volatile("global_load_dwordx4 %0, %1, off" : "=v"(d) : "v"(p));
}

#define SB __builtin_amdgcn_sched_barrier(0)

// ---------------- Kernel 1: gate softmax (f32) + x -> bf16 cast --------------
__global__ __launch_bounds__(256) void gate_cast_kernel(
    const float* __restrict__ x, const float* __restrict__ Wg,
    const float* __restrict__ bg, float* __restrict__ gout,
    unsigned short* __restrict__ xbf) {
  const int lane = threadIdx.x & 63;
  const int wid = threadIdx.x >> 6;
  const int row = blockIdx.x * 4 + wid;

  const f32x4* xr = (const f32x4*)(x + (size_t)row * DIN);
  f32x4 xv[4];
#pragma unroll
  for (int j = 0; j < 4; ++j) xv[j] = xr[j * 64 + lane];

  float acc[NE];
#pragma unroll
  for (int e = 0; e < NE; ++e) acc[e] = 0.f;

#pragma unroll
  for (int j = 0; j < 4; ++j) {
#pragma unroll
    for (int t = 0; t < 4; ++t) {
      const int i = j * 256 + lane * 4 + t;
      const f32x4* wrow = (const f32x4*)(Wg + (size_t)i * NE);
      const f32x4 w0 = wrow[0], w1 = wrow[1], w2 = wrow[2], w3 = wrow[3];
      const float xx = xv[j][t];
#pragma unroll
      for (int q = 0; q < 4; ++q) {
        acc[q]      = fmaf(xx, w0[q], acc[q]);
        acc[4 + q]  = fmaf(xx, w1[q], acc[4 + q]);
        acc[8 + q]  = fmaf(xx, w2[q], acc[8 + q]);
        acc[12 + q] = fmaf(xx, w3[q], acc[12 + q]);
      }
    }
  }
#pragma unroll
  for (int off = 32; off >= 1; off >>= 1) {
#pragma unroll
    for (int e = 0; e < NE; ++e) acc[e] += __shfl_xor(acc[e], off, 64);
  }
#pragma unroll
  for (int e = 0; e < NE; ++e) acc[e] += bg[e];
  float mx = acc[0];
#pragma unroll
  for (int e = 1; e < NE; ++e) mx = fmaxf(mx, acc[e]);
  float p[NE];
  float s = 0.f;
#pragma unroll
  for (int e = 0; e < NE; ++e) { p[e] = expf(acc[e] - mx); s += p[e]; }
  const float inv = 1.f / s;
  if (lane == 0) {
#pragma unroll
    for (int e = 0; e < NE; ++e) gout[(size_t)row * NE + e] = p[e] * inv;
  }
#pragma unroll
  for (int j = 0; j < 4; ++j) {
    short4_t o;
#pragma unroll
    for (int t = 0; t < 4; ++t) o[t] = (short)f32_to_bf16(xv[j][t]);
    *(short4_t*)(xbf + (size_t)row * DIN + j * 256 + lane * 4) = o;
  }
}

// ---- Kernel 2: We[e,i,o] f32 -> WeP bf16, MFMA-fragment-packed -------------
// Chunk (e, kt, cf, ksub): 64 lanes x 16B contiguous (1 KB). Lane l holds
// We[e][kt*64 + ksub*32 + (l>>4)*8 + j][cf*16 + (l&15)], j=0..7.
__global__ __launch_bounds__(256) void we_pack_kernel(
    const float* __restrict__ We, unsigned short* __restrict__ WeP) {
  __shared__ float tile[64][65];
  const int e = blockIdx.z, kt = blockIdx.y, ot = blockIdx.x;
  const int tr = threadIdx.x >> 4;
  const int tc = (threadIdx.x & 15) * 4;
  const float* src = We + (((size_t)e * DIN + kt * 64) * DOUT) + ot * 64;
#pragma unroll
  for (int rr = 0; rr < 64; rr += 16) {
    const f32x4 v = *(const f32x4*)(src + (size_t)(rr + tr) * DOUT + tc);
#pragma unroll
    for (int t = 0; t < 4; ++t) tile[rr + tr][tc + t] = v[t];
  }
  __syncthreads();
  // base chunk for this block: ((e*16+kt)*64 + ot*4) cf-chunks, 2 ksub each
  unsigned short* const dst =
      WeP + ((size_t)(e * 16 + kt) * 64 + ot * 4) * 1024;
#pragma unroll
  for (int h = 0; h < 2; ++h) {
    const int c = (int)threadIdx.x + h * 256;  // c = cf*128 + ksub*64 + l
    const int l = c & 63;
    const int ks = (c >> 6) & 1;
    const int cf = c >> 7;
    const int o = cf * 16 + (l & 15);
    const int i0 = ks * 32 + (l >> 4) * 8;
    bf16x8 w;
#pragma unroll
    for (int j = 0; j < 8; ++j) w[j] = (short)f32_to_bf16(tile[i0 + j][o]);
    *(bf16x8*)(dst + (size_t)c * 8) = w;  // elem offset c*8 == packed layout
  }
}

// ------------- Kernel 3: split-K MoE GEMM, B direct-to-registers -------------
// 8 waves 2Mx4N, per-wave 128x64. LDS holds A only (T2-swizzled, dbuf).
// B frags loaded straight from packed WeP to VGPRs (8 coalesced 16B loads
// per wave per tile, double-buffered regs). 2 barriers/tile:
//   W1-end: vmcnt(8) drains own Ah1 (leaves next B8) + barrier
//   boundary: vmcnt(2) drains next B8+Ah0 (leaves Ah1) + barrier
__global__ __launch_bounds__(512, 2) void moe_gemm_kernel(
    const unsigned short* __restrict__ xbf,   // [8192][1024] bf16
    const unsigned short* __restrict__ WeP,   // packed B fragments
    const float* __restrict__ g,              // [8192][16]
    const float* __restrict__ be,             // [16][1024]
    float* __restrict__ out0,                 // kh=0 -> d_out
    float* __restrict__ out1) {               // kh=1 -> partial ws
  __shared__ __align__(16) unsigned short As[2][BM * BK];  // 2x32 KiB
  __shared__ float gs[BM][NE];                             // 16 KiB

  const int tid = threadIdx.x;
  const int lane = tid & 63, wid = tid >> 6;
  const int wm = wid >> 2, wn = wid & 3;
  const int l15 = lane & 15, l4 = lane >> 4;

  const int bid = blockIdx.x;
  const int xcd = bid & 7, jj_ = bid >> 3;
  const int kh = xcd >> 2;
  const int brow = ((xcd & 3) * 8 + (jj_ >> 2)) * BM;
  const int bcol = (jj_ & 3) * BN;
  float* const outp = kh ? out1 : out0;

  // A LDS read bases (T2 swizzle depends only on l15,l4,ks)
  const int swz0 = (l4 * 16) ^ ((l15 & 7) << 4);
  const int swz1 = (64 + l4 * 16) ^ ((l15 & 7) << 4);
  const char* const ldsA0 =
      (const char*)&As[0][0] + (wm * 128 + l15) * 128 + swz0;
  const char* const ldsA1 =
      (const char*)&As[0][0] + (wm * 128 + l15) * 128 + swz1;

  // A staging (linear LDS dst, inverse-swizzled global src)
  const int srow = tid >> 3;
  const int lk = (((tid & 7) * 16) ^ ((srow & 7) << 4)) >> 1;
  const unsigned short* const aBase = xbf + (size_t)(brow + srow) * DIN + lk;
  char* const ldsStA = (char*)&As[0][0] + wid * 1024;

  // B packed base for this wave: + kh half, + wave col group, + lane
  const unsigned short* const bBase0 = WeP + (size_t)kh * 128 * 65536 +
                                       (size_t)(bcol / 16 + wn * 4) * 1024 +
                                       (size_t)lane * 8;

#define STA(BUF, CR, KC) \
  gl_lds16(aBase + (size_t)(CR) * DIN + (KC), \
           ldsStA + (BUF) * 32768 + (CR) * 128)
#define RD_A(KS, MI0, BUF)                                  \
  _Pragma("unroll") for (int d = 0; d < 4; ++d)             \
      af[d] = *(const bf16x8*)(((KS) ? ldsA1 : ldsA0) +     \
                               ((MI0) + d) * 2048 + (BUF) * 32768);
#define LOADB8(NXT, BP)                                           \
  gload16(NXT[0][0], (BP)); gload16(NXT[0][1], (BP) + 512);       \
  gload16(NXT[1][0], (BP) + 1024); gload16(NXT[1][1], (BP) + 1536); \
  gload16(NXT[2][0], (BP) + 2048); gload16(NXT[2][1], (BP) + 2560); \
  gload16(NXT[3][0], (BP) + 3072); gload16(NXT[3][1], (BP) + 3584);
#define MFMA_P(MI0, KS, BF)                                        \
  _Pragma("unroll") for (int d = 0; d < 4; ++d)                    \
  _Pragma("unroll") for (int ni = 0; ni < 4; ++ni)                 \
      acc[(MI0) + d][ni] = __builtin_amdgcn_mfma_f32_16x16x32_bf16(\
          af[d], BF[ni][KS], acc[(MI0) + d][ni], 0, 0, 0);

  {  // gate tile -> LDS
    const f32x4* gsrc = (const f32x4*)(g + (size_t)brow * NE);
    f32x4* gdst = (f32x4*)&gs[0][0];
    gdst[tid] = gsrc[tid];
    gdst[tid + 512] = gsrc[tid + 512];
  }

  bf16x8 bA[4][2], bB[4][2], af[4];

  // prologue: B(t0) 8 loads, then A(t0) h0, h1
  LOADB8(bA, bBase0);
  STA(0, 0, 0); STA(0, 128, 0);   // Ah0
  STA(0, 64, 0); STA(0, 192, 0);  // Ah1

  f32x4 acc[8][4];
#pragma unroll
  for (int mi = 0; mi < 8; ++mi)
#pragma unroll
    for (int ni = 0; ni < 4; ++ni) acc[mi][ni] = (f32x4){0.f, 0.f, 0.f, 0.f};

  asm volatile("s_waitcnt vmcnt(2) lgkmcnt(0)" ::: "memory");
  SB; __builtin_amdgcn_s_barrier(); SB;

#define TILE_BODY(T, BUF, CUR, NXT)                                            \
  {                                                                            \
    const int t_ = (T);                                                        \
    const bool hasNext = (t_ + 1) < NT;                                        \
    if ((t_ & 15) == 0 && t_ > 0) { /* expert boundary rescale */              \
      const int e = kh * 8 + (t_ >> 4);                                        \
      _Pragma("unroll") for (int mi = 0; mi < 8; ++mi) {                       \
        const int rb = wm * 128 + mi * 16 + l4 * 4;                            \
        _Pragma("unroll") for (int q = 0; q < 4; ++q) {                        \
          const float r = gs[rb + q][e - 1] *                                  \
                          __builtin_amdgcn_rcpf(fmaxf(gs[rb + q][e], 1e-30f)); \
          _Pragma("unroll") for (int ni = 0; ni < 4; ++ni)                     \
              acc[mi][ni][q] *= r;                                             \
        }                                                                      \
      }                                                                        \
    }                                                                          \
    /* ===== W1: mi0-3, both ks; prefetch next B ===== */                      \
    if (hasNext) {                                                             \
      const unsigned short* bp = bBase0 + (size_t)(t_ + 1) * 65536;            \
      LOADB8(NXT, bp);                                                         \
    }                                                                          \
    RD_A(0, 0, BUF);                                                           \
    __builtin_amdgcn_s_setprio(1); MFMA_P(0, 0, CUR);                          \
    __builtin_amdgcn_s_setprio(0);                                             \
    RD_A(1, 0, BUF);                                                           \
    __builtin_amdgcn_s_setprio(1); MFMA_P(0, 1, CUR);                          \
    __builtin_amdgcn_s_setprio(0);                                             \
    if (hasNext) { asm volatile("s_waitcnt vmcnt(8)" ::: "memory"); }          \
    else         { asm volatile("s_waitcnt vmcnt(0)" ::: "memory"); }          \
    SB; __builtin_amdgcn_s_barrier(); SB;                                      \
    /* ===== W2: mi4-7, both ks; stage next A ===== */                         \
    if (hasNext) {                                                             \
      const int kcN = ((t_ + 1) & 15) * 64;                                    \
      STA(BUF ^ 1, 0, kcN); STA(BUF ^ 1, 128, kcN);                            \
      STA(BUF ^ 1, 64, kcN); STA(BUF ^ 1, 192, kcN);                           \
    }                                                                          \
    RD_A(0, 4, BUF);                                                           \
    __builtin_amdgcn_s_setprio(1); MFMA_P(4, 0, CUR);                          \
    __builtin_amdgcn_s_setprio(0);                                             \
    RD_A(1, 4, BUF);                                                           \
    __builtin_amdgcn_s_setprio(1); MFMA_P(4, 1, CUR);                          \
    __builtin_amdgcn_s_setprio(0);                                             \
    if (hasNext) {                                                             \
      asm volatile("s_waitcnt vmcnt(2)" ::: "memory");                         \
      SB; __builtin_amdgcn_s_barrier(); SB;                                    \
    }                                                                          \
  }

  for (int tt = 0; tt < NT; tt += 2) {
    TILE_BODY(tt, 0, bA, bB);
    TILE_BODY(tt + 1, 1, bB, bA);
  }

  // epilogue: out = acc*g[eL] + sum_e g[e]*be[e,col]  (bias applied here)
  const int eL = kh * 8 + 7;
  float bv[8][4];
#pragma unroll
  for (int e8 = 0; e8 < 8; ++e8)
#pragma unroll
    for (int ni = 0; ni < 4; ++ni)
      bv[e8][ni] = be[(kh * 8 + e8) * DOUT + bcol + wn * 64 + ni * 16 + l15];
#pragma unroll
  for (int mi = 0; mi < 8; ++mi) {
    const int rb = wm * 128 + mi * 16 + l4 * 4;
#pragma unroll
    for (int q = 0; q < 4; ++q) {
      const int row = rb + q;
      const float gf = gs[row][eL];
      float b0 = 0.f, b1 = 0.f, b2 = 0.f, b3 = 0.f;
#pragma unroll
      for (int e8 = 0; e8 < 8; ++e8) {
        const float ge = gs[row][kh * 8 + e8];
        b0 = fmaf(ge, bv[e8][0], b0);
        b1 = fmaf(ge, bv[e8][1], b1);
        b2 = fmaf(ge, bv[e8][2], b2);
        b3 = fmaf(ge, bv[e8][3], b3);
      }
      const size_t orow = (size_t)brow + row;
      float* const orp = outp + orow * DOUT + bcol + wn * 64 + l15;
      orp[0]  = fmaf(acc[mi][0][q], gf, b0);
      orp[16] = fmaf(acc[mi][1][q], gf, b1);
      orp[32] = fmaf(acc[mi][2][q], gf, b2);
      orp[48] = fmaf(acc[mi][3][q], gf, b3);
    }
  }
#undef TILE_BODY
#undef MFMA_P
#undef LOADB8
#undef RD_A
#undef STA
}

// ---------------- Kernel 4: combine out += p1 --------------------------------
__global__ __launch_bounds__(256) void combine_kernel(
    float* __restrict__ out, const float* __restrict__ p1) {
  const size_t i = (size_t)blockIdx.x * 256 + threadIdx.x;  // f32x4 index
  f32x4 a = ((const f32x4*)out)[i];
  const f32x4 b = ((const f32x4*)p1)[i];
#pragma unroll
  for (int q = 0; q < 4; ++q) a[q] += b[q];
  ((f32x4*)out)[i] = a;
}

// ---------------------------------------------------------------------------
extern "C" void kernel_launch(void* const* d_in, const int* in_sizes, int n_in,
                              void* d_out, int out_size, void* d_ws, size_t ws_size,
                              hipStream_t stream) {
  const float* x  = (const float*)d_in[0];
  const float* Wg = (const float*)d_in[1];
  const float* bg = (const float*)d_in[2];
  const float* We = (const float*)d_in[3];
  const float* be = (const float*)d_in[4];
  float* out = (float*)d_out;

  // ws: xbf 16MB | WeP 32MB | g 512KB | p1 32MB  (total 80.5MB)
  char* ws = (char*)d_ws;
  unsigned short* xbf = (unsigned short*)ws;
  unsigned short* WeP = (unsigned short*)(ws + (size_t)NB * DIN * 2);
  float* g = (float*)(ws + (size_t)NB * DIN * 2 + (size_t)NE * DIN * DOUT * 2);
  float* p1 = (float*)(ws + (size_t)NB * DIN * 2 + (size_t)NE * DIN * DOUT * 2 +
                       (size_t)NB * NE * 4);

  gate_cast_kernel<<<dim3(NB / 4), 256, 0, stream>>>(x, Wg, bg, g, xbf);
  we_pack_kernel<<<dim3(DOUT / 64, DIN / 64, NE), 256, 0, stream>>>(We, WeP);
  moe_gemm_kernel<<<dim3(256), 512, 0, stream>>>(xbf, WeP, g, be, out, p1);
  combine_kernel<<<dim3(NB * DOUT / 4 / 256), 256, 0, stream>>>(out, p1);
}